// Round 9
// baseline (240.609 us; speedup 1.0000x reference)
//
#include <hip/hip_runtime.h>

// WindowAttention (Swin-3D) on MI355X / gfx950.
// R9: qkv epilogue de-scatter — q/k/v stored as [h][MP(padded token)][32] so
// the C-write needs no div/mod (dst + scale are block-uniform); x f32->f16
// cast fused into qkv A-staging (prep_xh and the xh buffer removed, ~50 MB
// traffic saved). attn unchanged from R8 except slice pointers; proj unchanged.

#define DIMD 384
#define NHH 12
#define HEADD 32
#define LL 343
#define NWW 64
#define NTOK (NWW * LL)            // 21952
#define MPT 176                    // m tiles (128 each)
#define MP (MPT * 128)             // 22528
#define LP 352                     // L padded to 22*16
#define QT 22
#define KS 40                      // attn Ks row stride (f16)
#define VTS 360                    // attn Vts row stride (f16)
#define PSB 40                     // attn P buffer row stride (f16)
#define MW 12                      // mask words per column
#define SCALE_ 0.17677669529663687f
#define LOG2E_ 1.4426950408889634f
#define NEGBIG_ (-1.0e4f)

typedef _Float16 f16;
typedef _Float16 v8h __attribute__((ext_vector_type(8)));
typedef _Float16 v4h __attribute__((ext_vector_type(4)));
typedef float v4f __attribute__((ext_vector_type(4)));

__device__ __forceinline__ void async_cp16(const void* g, void* l) {
    __builtin_amdgcn_global_load_lds(
        (const __attribute__((address_space(1))) void*)g,
        (__attribute__((address_space(3))) void*)l, 16, 0, 0);
}

// ---- workspace layout (bytes) ----
constexpr size_t HBUF = (size_t)NHH * MP * HEADD * 2;          // 17,301,504 per q/k/v
constexpr size_t OFF_Q    = 0;
constexpr size_t OFF_K    = OFF_Q  + HBUF;
constexpr size_t OFF_V    = OFF_K  + HBUF;
constexpr size_t OFF_AO   = OFF_V  + HBUF;                     // f16 [MP][384]
constexpr size_t OFF_BT   = OFF_AO + (size_t)MP * DIMD * 2;    // f32 biasT2 (NH,88,352,4) *log2e
constexpr size_t OFF_WT   = OFF_BT + (size_t)NHH * LP * LP * 4;
constexpr size_t OFF_PWT  = OFF_WT + (size_t)3 * DIMD * DIMD * 2;
constexpr size_t OFF_MTB  = OFF_PWT + (size_t)DIMD * DIMD * 2; // uint (NW, 352, 12)

// attn LDS: Ks + Vts + mask bits + single P buffer
constexpr int SMEM_ATTN = LP * KS * 2 + 32 * VTS * 2 + LP * MW * 4 + 8 * 16 * PSB * 2; // 78336

// ---------------- fused prep ----------------
#define S1 (3 * DIMD * DIMD)
#define S2 (DIMD * DIMD)
#define S3 (NHH * LP * LP)
#define S4 (NWW * MW * LP)
#define SPREP (S1 + S2 + S3 + S4)

__global__ __launch_bounds__(256) void prep_all(
    const float* __restrict__ qkv_w, f16* __restrict__ wt,
    const float* __restrict__ proj_w, f16* __restrict__ pwt,
    const float* __restrict__ table, const int* __restrict__ rel, float* __restrict__ btf,
    const int* __restrict__ mask, unsigned int* __restrict__ mtb) {
    int t = blockIdx.x * 256 + threadIdx.x;
    if (t < S1) {
        int e = t;
        int n = e / DIMD, k = e % DIMD;          // wt[n][k] = qkv_w[k][n]
        wt[e] = (f16)qkv_w[(size_t)k * (3 * DIMD) + n];
    } else if (t < S1 + S2) {
        int e = t - S1;
        int n = e / DIMD, k = e % DIMD;
        pwt[e] = (f16)proj_w[(size_t)k * DIMD + n];
    } else if (t < S1 + S2 + S3) {
        // biasT2[h][rq][col][e2] = bias(h, r=rq*4+e2, col)*log2e, pads -> -1e4
        int e = t - S1 - S2;
        int h = e / (LP * LP), rem = e % (LP * LP);
        int rq = rem / (LP * 4);
        int rem2 = rem % (LP * 4);
        int col = rem2 >> 2, e2 = rem2 & 3;
        int r = rq * 4 + e2;
        float v = NEGBIG_;
        if (col < LL && r < LL) v = table[(size_t)rel[r * LL + col] * NHH + h] * LOG2E_;
        btf[e] = v;
    } else if (t < SPREP) {
        int e = t - S1 - S2 - S3;
        int n = e / (MW * LP), rem = e % (MW * LP);
        int wg = rem / LP, col = rem % LP;
        unsigned int wd = 0;
        if (col < LL) {
            int rbase = wg * 32;
#pragma unroll 4
            for (int b = 0; b < 32; ++b) {
                int r = rbase + b;
                if (r < LL && mask[((size_t)n * LL + r) * LL + col]) wd |= (1u << b);
            }
        }
        mtb[((size_t)n * LP + col) * MW + wg] = wd;
    }
}

// ---------------- QKV GEMM (128x128, fused x-cast A staging, XCD swizzle) ----------------
__global__ __launch_bounds__(256) void qkv_gemm(
    const float* __restrict__ x, const f16* __restrict__ wt,
    f16* __restrict__ qb, f16* __restrict__ kb, f16* __restrict__ vb) {
    __shared__ f16 As[128 * 32];
    __shared__ f16 Bs[128 * 32];
    const int lin = blockIdx.x;
    const int m0 = ((lin / 72) * 8 + (lin & 7)) * 128;
    const int n0 = ((lin >> 3) % 9) * 128;
    const int tid = threadIdx.x;
    const int wave = tid >> 6, lane = tid & 63;
    const int quad = lane >> 4, l15 = lane & 15;
    const int wm = (wave >> 1) * 64, wn = (wave & 1) * 64;
    // B async staging geometry (wave-uniform base + lane*16B)
    const int srow = (lane >> 2);
    const int scol = (lane & 3) * 8;
    const f16* gb0 = wt + (size_t)(n0 + wave * 32 + srow) * DIMD + scol;
    const f16* gb1 = wt + (size_t)(n0 + wave * 32 + 16 + srow) * DIMD + scol;
    f16* lb0 = Bs + (wave * 2) * 512;
    f16* lb1 = Bs + (wave * 2 + 1) * 512;
    // A staging: f32 x loaded via VGPRs, cast, ds_write (fused prep_xh)
    int arow[4]; const float* asrc[4];
#pragma unroll
    for (int i = 0; i < 4; ++i) {
        int c = i * 256 + tid;
        arow[i] = c >> 3;
        int srcr = m0 + arow[i]; if (srcr >= NTOK) srcr = NTOK - 1;
        asrc[i] = x + (size_t)srcr * DIMD + (c & 7) * 4;
    }
    v4f acc[4][4] = {};
    for (int k0 = 0; k0 < DIMD; k0 += 32) {
        async_cp16(gb0 + k0, lb0);
        async_cp16(gb1 + k0, lb1);
#pragma unroll
        for (int i = 0; i < 4; ++i) {
            int c = i * 256 + tid;
            float4 v = *(const float4*)(asrc[i] + k0);
            v4h o; o[0] = (f16)v.x; o[1] = (f16)v.y; o[2] = (f16)v.z; o[3] = (f16)v.w;
            *(v4h*)(As + arow[i] * 32 + (c & 7) * 4) = o;
        }
        __syncthreads();
        v8h a[4], b[4];
#pragma unroll
        for (int i = 0; i < 4; ++i) a[i] = *(const v8h*)(As + (wm + i * 16 + l15) * 32 + quad * 8);
#pragma unroll
        for (int j = 0; j < 4; ++j) b[j] = *(const v8h*)(Bs + (wn + j * 16 + l15) * 32 + quad * 8);
#pragma unroll
        for (int i = 0; i < 4; ++i)
#pragma unroll
            for (int j = 0; j < 4; ++j)
                acc[i][j] = __builtin_amdgcn_mfma_f32_16x16x32_f16(a[i], b[j], acc[i][j], 0, 0, 0);
        __syncthreads();
    }
    // epilogue: block-uniform dst/scale, per-lane offset = one add
    const int t = n0 / DIMD;
    f16* dst = (t == 0) ? qb : (t == 1) ? kb : vb;
    const float sc = (t == 0) ? (SCALE_ * LOG2E_) : 1.0f;
    size_t hoff[4];
#pragma unroll
    for (int j = 0; j < 4; ++j) {
        int rem = (n0 - t * DIMD) + wn + j * 16 + l15;
        hoff[j] = (size_t)(rem >> 5) * ((size_t)MP * HEADD) + (rem & 31);
    }
#pragma unroll
    for (int i = 0; i < 4; ++i)
#pragma unroll
        for (int e = 0; e < 4; ++e) {
            int gm = m0 + wm + i * 16 + quad * 4 + e;
            if (gm < NTOK) {
                size_t g32 = (size_t)gm * HEADD;
#pragma unroll
                for (int j = 0; j < 4; ++j)
                    dst[hoff[j] + g32] = (f16)(acc[i][j][e] * sc);
            }
        }
}

// ---------------- attention (R8 body; [h][MP][32] q/k/v slices) ----------------
__global__ __launch_bounds__(512, 4) void attn_kernel(
    const f16* __restrict__ qb, const f16* __restrict__ kb, const f16* __restrict__ vb,
    const float* __restrict__ biasT, const unsigned int* __restrict__ mtb,
    f16* __restrict__ ao) {
    extern __shared__ char smem[];
    f16* Ks  = (f16*)smem;                            // [LP][KS]
    f16* Vts = Ks + LP * KS;                          // [32][VTS]
    unsigned int* mtbL = (unsigned int*)(Vts + 32 * VTS);  // [LP][MW]
    f16* Ps  = (f16*)(mtbL + LP * MW);                // [8 waves][16][PSB]
    const int n = blockIdx.x, h = blockIdx.y;
    const int tid = threadIdx.x, wave = tid >> 6, lane = tid & 63;
    const int quad = lane >> 4, l15 = lane & 15;
    const size_t slice = ((size_t)h * MP + n * LL) * HEADD;
    const f16* qg = qb + slice;
    const f16* kg = kb + slice;
    const f16* vg = vb + slice;
    for (int i = tid; i < LL * 8; i += 512) {
        int row = i >> 3, c4 = i & 7;
        *(ushort4*)(Ks + row * KS + c4 * 4) = *(const ushort4*)(kg + i * 4);
    }
    for (int i = tid; i < (LP - LL) * 8; i += 512) {
        int row = LL + (i >> 3), c4 = i & 7;
        *(ushort4*)(Ks + row * KS + c4 * 4) = make_ushort4(0, 0, 0, 0);
    }
    for (int i = tid; i < LL * 8; i += 512) {
        int key = i >> 3, c4 = (i & 7) * 4;
        ushort4 vv = *(const ushort4*)(vg + key * HEADD + c4);
        f16* d = Vts + c4 * VTS + key;
        d[0] = *(const f16*)&vv.x; d[VTS] = *(const f16*)&vv.y;
        d[2 * VTS] = *(const f16*)&vv.z; d[3 * VTS] = *(const f16*)&vv.w;
    }
    for (int i = tid; i < 32 * (LP - LL); i += 512) {
        int ch = i / (LP - LL), key = LL + i % (LP - LL);
        Vts[ch * VTS + key] = (f16)0.f;
    }
    {
        const unsigned int* mg = mtb + (size_t)n * LP * MW;
        for (int i = tid; i < LP * MW; i += 512) mtbL[i] = mg[i];
    }
    __syncthreads();
    f16* Pw = Ps + wave * (16 * PSB);
    const float* bth = biasT + (size_t)h * LP * LP;   // biasT2 layout [88][352][4]
    for (int qt = wave; qt < QT; qt += 8) {
        v8h af = *(const v8h*)(qg + (qt * 16 + l15) * HEADD + quad * 8);
        const int r0 = qt * 16 + quad * 4;
        const int rword = r0 >> 5, rsh = r0 & 31;
        const float* bq = bth + (size_t)(qt * 4 + quad) * (LP * 4);
        v4f rsum = {};
        v4f o0 = {}, o1 = {};
#pragma unroll
        for (int ktp = 0; ktp < 11; ++ktp) {
            v4f cin[2]; unsigned int mw[2]; v8h bf[2]; v4f s[2];
#pragma unroll
            for (int half = 0; half < 2; ++half) {
                const int col = (ktp * 2 + half) * 16 + l15;
                cin[half] = *(const v4f*)(bq + (size_t)col * 4);   // coalesced 16B
                mw[half] = mtbL[col * MW + rword];
                bf[half] = *(const v8h*)(Ks + col * KS + quad * 8);
            }
#pragma unroll
            for (int half = 0; half < 2; ++half) {
                v4f c = cin[half];
#pragma unroll
                for (int e = 0; e < 4; ++e)
                    if ((mw[half] >> (rsh + e)) & 1u) c[e] = NEGBIG_;
                s[half] = __builtin_amdgcn_mfma_f32_16x16x32_f16(af, bf[half], c, 0, 0, 0);
            }
#pragma unroll
            for (int half = 0; half < 2; ++half)
#pragma unroll
                for (int e = 0; e < 4; ++e) {
                    float p = __builtin_amdgcn_exp2f(s[half][e]);
                    rsum[e] += p;
                    Pw[(quad * 4 + e) * PSB + half * 16 + l15] = (f16)p;
                }
            v8h a  = *(const v8h*)(Pw + l15 * PSB + quad * 8);
            v8h b0 = *(const v8h*)(Vts + l15 * VTS + ktp * 32 + quad * 8);
            v8h b1 = *(const v8h*)(Vts + (16 + l15) * VTS + ktp * 32 + quad * 8);
            o0 = __builtin_amdgcn_mfma_f32_16x16x32_f16(a, b0, o0, 0, 0, 0);
            o1 = __builtin_amdgcn_mfma_f32_16x16x32_f16(a, b1, o1, 0, 0, 0);
        }
#pragma unroll
        for (int e = 0; e < 4; ++e) {
            float t = rsum[e];
            t += __shfl_xor(t, 1);
            t += __shfl_xor(t, 2);
            t += __shfl_xor(t, 4);
            t += __shfl_xor(t, 8);
            rsum[e] = t;
        }
#pragma unroll
        for (int e = 0; e < 4; ++e) {
            int r = r0 + e;
            if (r < LL) {
                float inv = 1.f / rsum[e];
                f16* orow = ao + ((size_t)(n * LL + r)) * DIMD + h * HEADD;
                orow[l15] = (f16)(o0[e] * inv);
                orow[16 + l15] = (f16)(o1[e] * inv);
            }
        }
    }
}

// ---------------- proj GEMM (128x128, async staging, XCD swizzle) ----------------
__global__ __launch_bounds__(256) void proj_gemm(
    const f16* __restrict__ ao, const f16* __restrict__ pwt,
    const float* __restrict__ pb, float* __restrict__ out) {
    __shared__ f16 As[128 * 32];
    __shared__ f16 Bs[128 * 32];
    const int lin = blockIdx.x;
    const int m0 = ((lin / 24) * 8 + (lin & 7)) * 128;
    const int n0 = ((lin >> 3) % 3) * 128;
    const int tid = threadIdx.x;
    const int wave = tid >> 6, lane = tid & 63;
    const int quad = lane >> 4, l15 = lane & 15;
    const int wm = (wave >> 1) * 64, wn = (wave & 1) * 64;
    const int srow = (lane >> 2);
    const int scol = (lane & 3) * 8;
    const f16* ga0 = ao + (size_t)(m0 + wave * 32 + srow) * DIMD + scol;
    const f16* ga1 = ao + (size_t)(m0 + wave * 32 + 16 + srow) * DIMD + scol;
    const f16* gb0 = pwt + (size_t)(n0 + wave * 32 + srow) * DIMD + scol;
    const f16* gb1 = pwt + (size_t)(n0 + wave * 32 + 16 + srow) * DIMD + scol;
    f16* la0 = As + (wave * 2) * 512;
    f16* la1 = As + (wave * 2 + 1) * 512;
    f16* lb0 = Bs + (wave * 2) * 512;
    f16* lb1 = Bs + (wave * 2 + 1) * 512;
    v4f acc[4][4] = {};
    for (int k0 = 0; k0 < DIMD; k0 += 32) {
        async_cp16(ga0 + k0, la0);
        async_cp16(ga1 + k0, la1);
        async_cp16(gb0 + k0, lb0);
        async_cp16(gb1 + k0, lb1);
        __syncthreads();
        v8h a[4], b[4];
#pragma unroll
        for (int i = 0; i < 4; ++i) a[i] = *(const v8h*)(As + (wm + i * 16 + l15) * 32 + quad * 8);
#pragma unroll
        for (int j = 0; j < 4; ++j) b[j] = *(const v8h*)(Bs + (wn + j * 16 + l15) * 32 + quad * 8);
#pragma unroll
        for (int i = 0; i < 4; ++i)
#pragma unroll
            for (int j = 0; j < 4; ++j)
                acc[i][j] = __builtin_amdgcn_mfma_f32_16x16x32_f16(a[i], b[j], acc[i][j], 0, 0, 0);
        __syncthreads();
    }
#pragma unroll
    for (int i = 0; i < 4; ++i)
#pragma unroll
        for (int e = 0; e < 4; ++e) {
            int gm = m0 + wm + i * 16 + quad * 4 + e;
            if (gm < NTOK) {
#pragma unroll
                for (int j = 0; j < 4; ++j) {
                    int gn = n0 + wn + j * 16 + l15;
                    out[(size_t)gm * DIMD + gn] = acc[i][j][e] + pb[gn];
                }
            }
        }
}

extern "C" void kernel_launch(void* const* d_in, const int* in_sizes, int n_in,
                              void* d_out, int out_size, void* d_ws, size_t ws_size,
                              hipStream_t stream) {
    const float* x      = (const float*)d_in[0];
    const float* qkv_w  = (const float*)d_in[1];
    const float* table  = (const float*)d_in[2];
    const float* proj_w = (const float*)d_in[3];
    const float* proj_b = (const float*)d_in[4];
    const int* mask     = (const int*)d_in[5];
    const int* rel      = (const int*)d_in[6];
    float* out = (float*)d_out;
    char* ws = (char*)d_ws;

    f16* q    = (f16*)(ws + OFF_Q);
    f16* k    = (f16*)(ws + OFF_K);
    f16* v    = (f16*)(ws + OFF_V);
    f16* ao   = (f16*)(ws + OFF_AO);
    float* bt = (float*)(ws + OFF_BT);
    f16* wt   = (f16*)(ws + OFF_WT);
    f16* pwt  = (f16*)(ws + OFF_PWT);
    unsigned int* mtb = (unsigned int*)(ws + OFF_MTB);

    hipFuncSetAttribute((const void*)attn_kernel,
                        hipFuncAttributeMaxDynamicSharedMemorySize, SMEM_ATTN);

    prep_all<<<(SPREP + 255) / 256, 256, 0, stream>>>(
        qkv_w, wt, proj_w, pwt, table, rel, bt, mask, mtb);
    qkv_gemm<<<dim3(MPT * 9), 256, 0, stream>>>(x, wt, q, k, v);
    attn_kernel<<<dim3(NWW, NHH), 512, SMEM_ATTN, stream>>>(q, k, v, bt, mtb, ao);
    proj_gemm<<<dim3(MPT * 3), 256, 0, stream>>>(ao, pwt, proj_b, out);
}

// Round 10
// 229.748 us; speedup vs baseline: 1.0473x; 1.0473x over previous
//
#include <hip/hip_runtime.h>

// WindowAttention (Swin-3D) on MI355X / gfx950.
// R10: recombine R8 + R9 winners. qkv staging = R8 (prep_xh f16 buffer, A and B
// both via async global_load_lds); qkv epilogue = R9 (q/k/v as [h][MP][32],
// block-uniform dst/scale, no div/mod). attn/proj unchanged.

#define DIMD 384
#define NHH 12
#define HEADD 32
#define LL 343
#define NWW 64
#define NTOK (NWW * LL)            // 21952
#define MPT 176                    // m tiles (128 each)
#define MP (MPT * 128)             // 22528
#define LP 352                     // L padded to 22*16
#define QT 22
#define KS 40                      // attn Ks row stride (f16)
#define VTS 360                    // attn Vts row stride (f16)
#define PSB 40                     // attn P buffer row stride (f16)
#define MW 12                      // mask words per column
#define SCALE_ 0.17677669529663687f
#define LOG2E_ 1.4426950408889634f
#define NEGBIG_ (-1.0e4f)

typedef _Float16 f16;
typedef _Float16 v8h __attribute__((ext_vector_type(8)));
typedef _Float16 v4h __attribute__((ext_vector_type(4)));
typedef float v4f __attribute__((ext_vector_type(4)));

__device__ __forceinline__ void async_cp16(const void* g, void* l) {
    __builtin_amdgcn_global_load_lds(
        (const __attribute__((address_space(1))) void*)g,
        (__attribute__((address_space(3))) void*)l, 16, 0, 0);
}

// ---- workspace layout (bytes) ----
constexpr size_t HBUF = (size_t)NHH * MP * HEADD * 2;          // per q/k/v
constexpr size_t OFF_Q    = 0;
constexpr size_t OFF_K    = OFF_Q  + HBUF;
constexpr size_t OFF_V    = OFF_K  + HBUF;
constexpr size_t OFF_AO   = OFF_V  + HBUF;                     // f16 [MP][384]; xh then AO
constexpr size_t OFF_BT   = OFF_AO + (size_t)MP * DIMD * 2;    // f32 biasT2 (NH,88,352,4) *log2e
constexpr size_t OFF_WT   = OFF_BT + (size_t)NHH * LP * LP * 4;
constexpr size_t OFF_PWT  = OFF_WT + (size_t)3 * DIMD * DIMD * 2;
constexpr size_t OFF_MTB  = OFF_PWT + (size_t)DIMD * DIMD * 2; // uint (NW, 352, 12)

// attn LDS: Ks + Vts + mask bits + single P buffer
constexpr int SMEM_ATTN = LP * KS * 2 + 32 * VTS * 2 + LP * MW * 4 + 8 * 16 * PSB * 2; // 78336

// ---------------- fused prep ----------------
#define S0 (NTOK * DIMD / 4)
#define S1 (3 * DIMD * DIMD)
#define S2 (DIMD * DIMD)
#define S3 (NHH * LP * LP)
#define S4 (NWW * MW * LP)
#define SPREP (S0 + S1 + S2 + S3 + S4)

__global__ __launch_bounds__(256) void prep_all(
    const float* __restrict__ x, f16* __restrict__ xh,
    const float* __restrict__ qkv_w, f16* __restrict__ wt,
    const float* __restrict__ proj_w, f16* __restrict__ pwt,
    const float* __restrict__ table, const int* __restrict__ rel, float* __restrict__ btf,
    const int* __restrict__ mask, unsigned int* __restrict__ mtb) {
    int t = blockIdx.x * 256 + threadIdx.x;
    if (t < S0) {
        float4 v = *(const float4*)(x + (size_t)t * 4);
        v4h o; o[0] = (f16)v.x; o[1] = (f16)v.y; o[2] = (f16)v.z; o[3] = (f16)v.w;
        *(v4h*)(xh + (size_t)t * 4) = o;
    } else if (t < S0 + S1) {
        int e = t - S0;
        int n = e / DIMD, k = e % DIMD;          // wt[n][k] = qkv_w[k][n]
        wt[e] = (f16)qkv_w[(size_t)k * (3 * DIMD) + n];
    } else if (t < S0 + S1 + S2) {
        int e = t - S0 - S1;
        int n = e / DIMD, k = e % DIMD;
        pwt[e] = (f16)proj_w[(size_t)k * DIMD + n];
    } else if (t < S0 + S1 + S2 + S3) {
        // biasT2[h][rq][col][e2] = bias(h, r=rq*4+e2, col)*log2e, pads -> -1e4
        int e = t - S0 - S1 - S2;
        int h = e / (LP * LP), rem = e % (LP * LP);
        int rq = rem / (LP * 4);
        int rem2 = rem % (LP * 4);
        int col = rem2 >> 2, e2 = rem2 & 3;
        int r = rq * 4 + e2;
        float v = NEGBIG_;
        if (col < LL && r < LL) v = table[(size_t)rel[r * LL + col] * NHH + h] * LOG2E_;
        btf[e] = v;
    } else if (t < SPREP) {
        int e = t - S0 - S1 - S2 - S3;
        int n = e / (MW * LP), rem = e % (MW * LP);
        int wg = rem / LP, col = rem % LP;
        unsigned int wd = 0;
        if (col < LL) {
            int rbase = wg * 32;
#pragma unroll 4
            for (int b = 0; b < 32; ++b) {
                int r = rbase + b;
                if (r < LL && mask[((size_t)n * LL + r) * LL + col]) wd |= (1u << b);
            }
        }
        mtb[((size_t)n * LP + col) * MW + wg] = wd;
    }
}

// ---------------- QKV GEMM (128x128, async staging, XCD swizzle, descattered epilogue) ----------------
__global__ __launch_bounds__(256) void qkv_gemm(
    const f16* __restrict__ xh, const f16* __restrict__ wt,
    f16* __restrict__ qb, f16* __restrict__ kb, f16* __restrict__ vb) {
    __shared__ f16 As[128 * 32];
    __shared__ f16 Bs[128 * 32];
    const int lin = blockIdx.x;
    const int m0 = ((lin / 72) * 8 + (lin & 7)) * 128;
    const int n0 = ((lin >> 3) % 9) * 128;
    const int tid = threadIdx.x;
    const int wave = tid >> 6, lane = tid & 63;
    const int quad = lane >> 4, l15 = lane & 15;
    const int wm = (wave >> 1) * 64, wn = (wave & 1) * 64;
    const int srow = (lane >> 2);
    const int scol = (lane & 3) * 8;
    const f16* ga0 = xh + (size_t)(m0 + wave * 32 + srow) * DIMD + scol;
    const f16* ga1 = xh + (size_t)(m0 + wave * 32 + 16 + srow) * DIMD + scol;
    const f16* gb0 = wt + (size_t)(n0 + wave * 32 + srow) * DIMD + scol;
    const f16* gb1 = wt + (size_t)(n0 + wave * 32 + 16 + srow) * DIMD + scol;
    f16* la0 = As + (wave * 2) * 512;
    f16* la1 = As + (wave * 2 + 1) * 512;
    f16* lb0 = Bs + (wave * 2) * 512;
    f16* lb1 = Bs + (wave * 2 + 1) * 512;
    v4f acc[4][4] = {};
    for (int k0 = 0; k0 < DIMD; k0 += 32) {
        async_cp16(ga0 + k0, la0);
        async_cp16(ga1 + k0, la1);
        async_cp16(gb0 + k0, lb0);
        async_cp16(gb1 + k0, lb1);
        __syncthreads();
        v8h a[4], b[4];
#pragma unroll
        for (int i = 0; i < 4; ++i) a[i] = *(const v8h*)(As + (wm + i * 16 + l15) * 32 + quad * 8);
#pragma unroll
        for (int j = 0; j < 4; ++j) b[j] = *(const v8h*)(Bs + (wn + j * 16 + l15) * 32 + quad * 8);
#pragma unroll
        for (int i = 0; i < 4; ++i)
#pragma unroll
            for (int j = 0; j < 4; ++j)
                acc[i][j] = __builtin_amdgcn_mfma_f32_16x16x32_f16(a[i], b[j], acc[i][j], 0, 0, 0);
        __syncthreads();
    }
    // epilogue: block-uniform dst/scale, per-lane offset = one add
    const int t = n0 / DIMD;
    f16* dst = (t == 0) ? qb : (t == 1) ? kb : vb;
    const float sc = (t == 0) ? (SCALE_ * LOG2E_) : 1.0f;
    size_t hoff[4];
#pragma unroll
    for (int j = 0; j < 4; ++j) {
        int rem = (n0 - t * DIMD) + wn + j * 16 + l15;
        hoff[j] = (size_t)(rem >> 5) * ((size_t)MP * HEADD) + (rem & 31);
    }
#pragma unroll
    for (int i = 0; i < 4; ++i)
#pragma unroll
        for (int e = 0; e < 4; ++e) {
            int gm = m0 + wm + i * 16 + quad * 4 + e;
            if (gm < NTOK) {
                size_t g32 = (size_t)gm * HEADD;
#pragma unroll
                for (int j = 0; j < 4; ++j)
                    dst[hoff[j] + g32] = (f16)(acc[i][j][e] * sc);
            }
        }
}

// ---------------- attention ([h][MP][32] q/k/v slices) ----------------
__global__ __launch_bounds__(512, 4) void attn_kernel(
    const f16* __restrict__ qb, const f16* __restrict__ kb, const f16* __restrict__ vb,
    const float* __restrict__ biasT, const unsigned int* __restrict__ mtb,
    f16* __restrict__ ao) {
    extern __shared__ char smem[];
    f16* Ks  = (f16*)smem;                            // [LP][KS]
    f16* Vts = Ks + LP * KS;                          // [32][VTS]
    unsigned int* mtbL = (unsigned int*)(Vts + 32 * VTS);  // [LP][MW]
    f16* Ps  = (f16*)(mtbL + LP * MW);                // [8 waves][16][PSB]
    const int n = blockIdx.x, h = blockIdx.y;
    const int tid = threadIdx.x, wave = tid >> 6, lane = tid & 63;
    const int quad = lane >> 4, l15 = lane & 15;
    const size_t slice = ((size_t)h * MP + n * LL) * HEADD;
    const f16* qg = qb + slice;
    const f16* kg = kb + slice;
    const f16* vg = vb + slice;
    for (int i = tid; i < LL * 8; i += 512) {
        int row = i >> 3, c4 = i & 7;
        *(ushort4*)(Ks + row * KS + c4 * 4) = *(const ushort4*)(kg + i * 4);
    }
    for (int i = tid; i < (LP - LL) * 8; i += 512) {
        int row = LL + (i >> 3), c4 = i & 7;
        *(ushort4*)(Ks + row * KS + c4 * 4) = make_ushort4(0, 0, 0, 0);
    }
    for (int i = tid; i < LL * 8; i += 512) {
        int key = i >> 3, c4 = (i & 7) * 4;
        ushort4 vv = *(const ushort4*)(vg + key * HEADD + c4);
        f16* d = Vts + c4 * VTS + key;
        d[0] = *(const f16*)&vv.x; d[VTS] = *(const f16*)&vv.y;
        d[2 * VTS] = *(const f16*)&vv.z; d[3 * VTS] = *(const f16*)&vv.w;
    }
    for (int i = tid; i < 32 * (LP - LL); i += 512) {
        int ch = i / (LP - LL), key = LL + i % (LP - LL);
        Vts[ch * VTS + key] = (f16)0.f;
    }
    {
        const unsigned int* mg = mtb + (size_t)n * LP * MW;
        for (int i = tid; i < LP * MW; i += 512) mtbL[i] = mg[i];
    }
    __syncthreads();
    f16* Pw = Ps + wave * (16 * PSB);
    const float* bth = biasT + (size_t)h * LP * LP;   // biasT2 layout [88][352][4]
    for (int qt = wave; qt < QT; qt += 8) {
        v8h af = *(const v8h*)(qg + (qt * 16 + l15) * HEADD + quad * 8);
        const int r0 = qt * 16 + quad * 4;
        const int rword = r0 >> 5, rsh = r0 & 31;
        const float* bq = bth + (size_t)(qt * 4 + quad) * (LP * 4);
        v4f rsum = {};
        v4f o0 = {}, o1 = {};
#pragma unroll
        for (int ktp = 0; ktp < 11; ++ktp) {
            v4f cin[2]; unsigned int mw[2]; v8h bf[2]; v4f s[2];
#pragma unroll
            for (int half = 0; half < 2; ++half) {
                const int col = (ktp * 2 + half) * 16 + l15;
                cin[half] = *(const v4f*)(bq + (size_t)col * 4);   // coalesced 16B
                mw[half] = mtbL[col * MW + rword];
                bf[half] = *(const v8h*)(Ks + col * KS + quad * 8);
            }
#pragma unroll
            for (int half = 0; half < 2; ++half) {
                v4f c = cin[half];
#pragma unroll
                for (int e = 0; e < 4; ++e)
                    if ((mw[half] >> (rsh + e)) & 1u) c[e] = NEGBIG_;
                s[half] = __builtin_amdgcn_mfma_f32_16x16x32_f16(af, bf[half], c, 0, 0, 0);
            }
#pragma unroll
            for (int half = 0; half < 2; ++half)
#pragma unroll
                for (int e = 0; e < 4; ++e) {
                    float p = __builtin_amdgcn_exp2f(s[half][e]);
                    rsum[e] += p;
                    Pw[(quad * 4 + e) * PSB + half * 16 + l15] = (f16)p;
                }
            v8h a  = *(const v8h*)(Pw + l15 * PSB + quad * 8);
            v8h b0 = *(const v8h*)(Vts + l15 * VTS + ktp * 32 + quad * 8);
            v8h b1 = *(const v8h*)(Vts + (16 + l15) * VTS + ktp * 32 + quad * 8);
            o0 = __builtin_amdgcn_mfma_f32_16x16x32_f16(a, b0, o0, 0, 0, 0);
            o1 = __builtin_amdgcn_mfma_f32_16x16x32_f16(a, b1, o1, 0, 0, 0);
        }
#pragma unroll
        for (int e = 0; e < 4; ++e) {
            float t = rsum[e];
            t += __shfl_xor(t, 1);
            t += __shfl_xor(t, 2);
            t += __shfl_xor(t, 4);
            t += __shfl_xor(t, 8);
            rsum[e] = t;
        }
#pragma unroll
        for (int e = 0; e < 4; ++e) {
            int r = r0 + e;
            if (r < LL) {
                float inv = 1.f / rsum[e];
                f16* orow = ao + ((size_t)(n * LL + r)) * DIMD + h * HEADD;
                orow[l15] = (f16)(o0[e] * inv);
                orow[16 + l15] = (f16)(o1[e] * inv);
            }
        }
    }
}

// ---------------- proj GEMM (128x128, async staging, XCD swizzle) ----------------
__global__ __launch_bounds__(256) void proj_gemm(
    const f16* __restrict__ ao, const f16* __restrict__ pwt,
    const float* __restrict__ pb, float* __restrict__ out) {
    __shared__ f16 As[128 * 32];
    __shared__ f16 Bs[128 * 32];
    const int lin = blockIdx.x;
    const int m0 = ((lin / 24) * 8 + (lin & 7)) * 128;
    const int n0 = ((lin >> 3) % 3) * 128;
    const int tid = threadIdx.x;
    const int wave = tid >> 6, lane = tid & 63;
    const int quad = lane >> 4, l15 = lane & 15;
    const int wm = (wave >> 1) * 64, wn = (wave & 1) * 64;
    const int srow = (lane >> 2);
    const int scol = (lane & 3) * 8;
    const f16* ga0 = ao + (size_t)(m0 + wave * 32 + srow) * DIMD + scol;
    const f16* ga1 = ao + (size_t)(m0 + wave * 32 + 16 + srow) * DIMD + scol;
    const f16* gb0 = pwt + (size_t)(n0 + wave * 32 + srow) * DIMD + scol;
    const f16* gb1 = pwt + (size_t)(n0 + wave * 32 + 16 + srow) * DIMD + scol;
    f16* la0 = As + (wave * 2) * 512;
    f16* la1 = As + (wave * 2 + 1) * 512;
    f16* lb0 = Bs + (wave * 2) * 512;
    f16* lb1 = Bs + (wave * 2 + 1) * 512;
    v4f acc[4][4] = {};
    for (int k0 = 0; k0 < DIMD; k0 += 32) {
        async_cp16(ga0 + k0, la0);
        async_cp16(ga1 + k0, la1);
        async_cp16(gb0 + k0, lb0);
        async_cp16(gb1 + k0, lb1);
        __syncthreads();
        v8h a[4], b[4];
#pragma unroll
        for (int i = 0; i < 4; ++i) a[i] = *(const v8h*)(As + (wm + i * 16 + l15) * 32 + quad * 8);
#pragma unroll
        for (int j = 0; j < 4; ++j) b[j] = *(const v8h*)(Bs + (wn + j * 16 + l15) * 32 + quad * 8);
#pragma unroll
        for (int i = 0; i < 4; ++i)
#pragma unroll
            for (int j = 0; j < 4; ++j)
                acc[i][j] = __builtin_amdgcn_mfma_f32_16x16x32_f16(a[i], b[j], acc[i][j], 0, 0, 0);
        __syncthreads();
    }
#pragma unroll
    for (int i = 0; i < 4; ++i)
#pragma unroll
        for (int e = 0; e < 4; ++e) {
            int gm = m0 + wm + i * 16 + quad * 4 + e;
            if (gm < NTOK) {
#pragma unroll
                for (int j = 0; j < 4; ++j) {
                    int gn = n0 + wn + j * 16 + l15;
                    out[(size_t)gm * DIMD + gn] = acc[i][j][e] + pb[gn];
                }
            }
        }
}

extern "C" void kernel_launch(void* const* d_in, const int* in_sizes, int n_in,
                              void* d_out, int out_size, void* d_ws, size_t ws_size,
                              hipStream_t stream) {
    const float* x      = (const float*)d_in[0];
    const float* qkv_w  = (const float*)d_in[1];
    const float* table  = (const float*)d_in[2];
    const float* proj_w = (const float*)d_in[3];
    const float* proj_b = (const float*)d_in[4];
    const int* mask     = (const int*)d_in[5];
    const int* rel      = (const int*)d_in[6];
    float* out = (float*)d_out;
    char* ws = (char*)d_ws;

    f16* q    = (f16*)(ws + OFF_Q);
    f16* k    = (f16*)(ws + OFF_K);
    f16* v    = (f16*)(ws + OFF_V);
    f16* xh   = (f16*)(ws + OFF_AO);   // xh and ao share the [MP][384] buffer
    f16* ao   = (f16*)(ws + OFF_AO);
    float* bt = (float*)(ws + OFF_BT);
    f16* wt   = (f16*)(ws + OFF_WT);
    f16* pwt  = (f16*)(ws + OFF_PWT);
    unsigned int* mtb = (unsigned int*)(ws + OFF_MTB);

    hipFuncSetAttribute((const void*)attn_kernel,
                        hipFuncAttributeMaxDynamicSharedMemorySize, SMEM_ATTN);

    prep_all<<<(SPREP + 255) / 256, 256, 0, stream>>>(
        x, xh, qkv_w, wt, proj_w, pwt, table, rel, bt, mask, mtb);
    qkv_gemm<<<dim3(MPT * 9), 256, 0, stream>>>(xh, wt, q, k, v);
    attn_kernel<<<dim3(NWW, NHH), 512, SMEM_ATTN, stream>>>(q, k, v, bt, mtb, ao);
    proj_gemm<<<dim3(MPT * 3), 256, 0, stream>>>(ao, pwt, proj_b, out);
}

// Round 13
// 226.973 us; speedup vs baseline: 1.0601x; 1.0122x over previous
//
#include <hip/hip_runtime.h>

// WindowAttention (Swin-3D) on MI355X / gfx950.
// R13 = R12 with the second qkv epilogue bug fixed: the coalesced store chunk
// is 8 f16 (16B, v8h) — R11/R12 used ushort4 (4 f16) with 8-col indexing, so
// half of every head's channels were never written. attn unchanged from R11
// (depth-1 bias prefetch + MFMA ones-column rsum).

#define DIMD 384
#define NHH 12
#define HEADD 32
#define LL 343
#define NWW 64
#define NTOK (NWW * LL)            // 21952
#define MPT 176                    // m tiles (128 each)
#define MP (MPT * 128)             // 22528
#define LP 352                     // L padded to 22*16
#define QT 22
#define KS 40                      // attn Ks row stride (f16)
#define VTS 360                    // attn Vts row stride (f16)
#define PSB 40                     // attn P buffer row stride (f16)
#define MW 12                      // mask words per column
#define CSS 136                    // qkv epilogue LDS stride (f16)
#define SCALE_ 0.17677669529663687f
#define LOG2E_ 1.4426950408889634f
#define NEGBIG_ (-1.0e4f)

typedef _Float16 f16;
typedef _Float16 v8h __attribute__((ext_vector_type(8)));
typedef _Float16 v4h __attribute__((ext_vector_type(4)));
typedef float v4f __attribute__((ext_vector_type(4)));

__device__ __forceinline__ void async_cp16(const void* g, void* l) {
    __builtin_amdgcn_global_load_lds(
        (const __attribute__((address_space(1))) void*)g,
        (__attribute__((address_space(3))) void*)l, 16, 0, 0);
}

// ---- workspace layout (bytes) ----
constexpr size_t HBUF = (size_t)NHH * MP * HEADD * 2;          // per q/k/v
constexpr size_t OFF_Q    = 0;
constexpr size_t OFF_K    = OFF_Q  + HBUF;
constexpr size_t OFF_V    = OFF_K  + HBUF;
constexpr size_t OFF_AO   = OFF_V  + HBUF;                     // f16 [MP][384]; xh then AO
constexpr size_t OFF_BT   = OFF_AO + (size_t)MP * DIMD * 2;    // f32 biasT2 (NH,88,352,4) *log2e
constexpr size_t OFF_WT   = OFF_BT + (size_t)NHH * LP * LP * 4;
constexpr size_t OFF_PWT  = OFF_WT + (size_t)3 * DIMD * DIMD * 2;
constexpr size_t OFF_MTB  = OFF_PWT + (size_t)DIMD * DIMD * 2; // uint (NW, 352, 12)

// attn LDS: Ks + Vts + mask bits + single P buffer
constexpr int SMEM_ATTN = LP * KS * 2 + 32 * VTS * 2 + LP * MW * 4 + 8 * 16 * PSB * 2; // 78336

// ---------------- fused prep ----------------
#define S0 (NTOK * DIMD / 4)
#define S1 (3 * DIMD * DIMD)
#define S2 (DIMD * DIMD)
#define S3 (NHH * LP * LP)
#define S4 (NWW * MW * LP)
#define SPREP (S0 + S1 + S2 + S3 + S4)

__global__ __launch_bounds__(256) void prep_all(
    const float* __restrict__ x, f16* __restrict__ xh,
    const float* __restrict__ qkv_w, f16* __restrict__ wt,
    const float* __restrict__ proj_w, f16* __restrict__ pwt,
    const float* __restrict__ table, const int* __restrict__ rel, float* __restrict__ btf,
    const int* __restrict__ mask, unsigned int* __restrict__ mtb) {
    int t = blockIdx.x * 256 + threadIdx.x;
    if (t < S0) {
        float4 v = *(const float4*)(x + (size_t)t * 4);
        v4h o; o[0] = (f16)v.x; o[1] = (f16)v.y; o[2] = (f16)v.z; o[3] = (f16)v.w;
        *(v4h*)(xh + (size_t)t * 4) = o;
    } else if (t < S0 + S1) {
        int e = t - S0;
        int n = e / DIMD, k = e % DIMD;          // wt[n][k] = qkv_w[k][n]
        wt[e] = (f16)qkv_w[(size_t)k * (3 * DIMD) + n];
    } else if (t < S0 + S1 + S2) {
        int e = t - S0 - S1;
        int n = e / DIMD, k = e % DIMD;
        pwt[e] = (f16)proj_w[(size_t)k * DIMD + n];
    } else if (t < S0 + S1 + S2 + S3) {
        // biasT2[h][rq][col][e2] = bias(h, r=rq*4+e2, col)*log2e, pads -> -1e4
        int e = t - S0 - S1 - S2;
        int h = e / (LP * LP), rem = e % (LP * LP);
        int rq = rem / (LP * 4);
        int rem2 = rem % (LP * 4);
        int col = rem2 >> 2, e2 = rem2 & 3;
        int r = rq * 4 + e2;
        float v = NEGBIG_;
        if (col < LL && r < LL) v = table[(size_t)rel[r * LL + col] * NHH + h] * LOG2E_;
        btf[e] = v;
    } else if (t < SPREP) {
        int e = t - S0 - S1 - S2 - S3;
        int n = e / (MW * LP), rem = e % (MW * LP);
        int wg = rem / LP, col = rem % LP;
        unsigned int wd = 0;
        if (col < LL) {
            int rbase = wg * 32;
#pragma unroll 4
            for (int b = 0; b < 32; ++b) {
                int r = rbase + b;
                if (r < LL && mask[((size_t)n * LL + r) * LL + col]) wd |= (1u << b);
            }
        }
        mtb[((size_t)n * LP + col) * MW + wg] = wd;
    }
}

// ---------------- QKV GEMM (128x128, async staging, XCD swizzle, LDS epilogue) ----------------
__global__ __launch_bounds__(256) void qkv_gemm(
    const f16* __restrict__ xh, const f16* __restrict__ wt,
    f16* __restrict__ qb, f16* __restrict__ kb, f16* __restrict__ vb) {
    __shared__ f16 ABs[8192];
    f16* As = ABs;
    f16* Bs = ABs + 4096;
    const int lin = blockIdx.x;
    const int m0 = ((lin / 72) * 8 + (lin & 7)) * 128;
    const int n0 = ((lin >> 3) % 9) * 128;
    const int tid = threadIdx.x;
    const int wave = tid >> 6, lane = tid & 63;
    const int quad = lane >> 4, l15 = lane & 15;
    const int wm = (wave >> 1) * 64, wn = (wave & 1) * 64;
    const int srow = (lane >> 2);
    const int scol = (lane & 3) * 8;
    const f16* ga0 = xh + (size_t)(m0 + wave * 32 + srow) * DIMD + scol;
    const f16* ga1 = xh + (size_t)(m0 + wave * 32 + 16 + srow) * DIMD + scol;
    const f16* gb0 = wt + (size_t)(n0 + wave * 32 + srow) * DIMD + scol;
    const f16* gb1 = wt + (size_t)(n0 + wave * 32 + 16 + srow) * DIMD + scol;
    f16* la0 = As + (wave * 2) * 512;
    f16* la1 = As + (wave * 2 + 1) * 512;
    f16* lb0 = Bs + (wave * 2) * 512;
    f16* lb1 = Bs + (wave * 2 + 1) * 512;
    v4f acc[4][4] = {};
    for (int k0 = 0; k0 < DIMD; k0 += 32) {
        async_cp16(ga0 + k0, la0);
        async_cp16(ga1 + k0, la1);
        async_cp16(gb0 + k0, lb0);
        async_cp16(gb1 + k0, lb1);
        __syncthreads();
        v8h a[4], b[4];
#pragma unroll
        for (int i = 0; i < 4; ++i) a[i] = *(const v8h*)(As + (wm + i * 16 + l15) * 32 + quad * 8);
#pragma unroll
        for (int j = 0; j < 4; ++j) b[j] = *(const v8h*)(Bs + (wn + j * 16 + l15) * 32 + quad * 8);
#pragma unroll
        for (int i = 0; i < 4; ++i)
#pragma unroll
            for (int j = 0; j < 4; ++j)
                acc[i][j] = __builtin_amdgcn_mfma_f32_16x16x32_f16(a[i], b[j], acc[i][j], 0, 0, 0);
        __syncthreads();
    }
    // epilogue: LDS-transposed coalesced stores into [h][MP][32] layout
    const int t = n0 / DIMD;
    f16* dst = (t == 0) ? qb : (t == 1) ? kb : vb;
    const float sc = (t == 0) ? (SCALE_ * LOG2E_) : 1.0f;
    const int nrel = n0 - t * DIMD;     // 0/128/256 within this third
    f16* Cs = ABs;                      // 32 x CSS f16 = 8704 B (within 16 KB)
    const int rl0 = (wave >> 1) * 16 + quad * 4;
#pragma unroll
    for (int i = 0; i < 4; ++i) {
#pragma unroll
        for (int e = 0; e < 4; ++e)
#pragma unroll
            for (int j = 0; j < 4; ++j)
                Cs[(rl0 + e) * CSS + wn + j * 16 + l15] = (f16)(acc[i][j][e] * sc);
        __syncthreads();
#pragma unroll
        for (int c = 0; c < 2; ++c) {
            int idx = c * 256 + tid;
            int rl = idx >> 4, col8 = (idx & 15) * 8;
            int gm = m0 + ((rl < 16) ? (i * 16 + rl) : (48 + i * 16 + rl));
            if (gm < NTOK) {
                int col = nrel + col8;          // global column within this third
                size_t off = (size_t)(col >> 5) * ((size_t)MP * HEADD)
                           + (col & 31) + (size_t)gm * HEADD;
                *(v8h*)(dst + off) = *(const v8h*)(Cs + rl * CSS + col8);  // 8 f16 = 16B
            }
        }
        __syncthreads();
    }
}

// ---------------- attention ([h][MP][32] slices, prefetched bias, MFMA rsum) ----------------
__global__ __launch_bounds__(512, 4) void attn_kernel(
    const f16* __restrict__ qb, const f16* __restrict__ kb, const f16* __restrict__ vb,
    const float* __restrict__ biasT, const unsigned int* __restrict__ mtb,
    f16* __restrict__ ao) {
    extern __shared__ char smem[];
    f16* Ks  = (f16*)smem;                            // [LP][KS]
    f16* Vts = Ks + LP * KS;                          // [32][VTS]
    unsigned int* mtbL = (unsigned int*)(Vts + 32 * VTS);  // [LP][MW]
    f16* Ps  = (f16*)(mtbL + LP * MW);                // [8 waves][16][PSB]
    const int n = blockIdx.x, h = blockIdx.y;
    const int tid = threadIdx.x, wave = tid >> 6, lane = tid & 63;
    const int quad = lane >> 4, l15 = lane & 15;
    const size_t slice = ((size_t)h * MP + n * LL) * HEADD;
    const f16* qg = qb + slice;
    const f16* kg = kb + slice;
    const f16* vg = vb + slice;
    for (int i = tid; i < LL * 8; i += 512) {
        int row = i >> 3, c4 = i & 7;
        *(ushort4*)(Ks + row * KS + c4 * 4) = *(const ushort4*)(kg + i * 4);
    }
    for (int i = tid; i < (LP - LL) * 8; i += 512) {
        int row = LL + (i >> 3), c4 = i & 7;
        *(ushort4*)(Ks + row * KS + c4 * 4) = make_ushort4(0, 0, 0, 0);
    }
    for (int i = tid; i < LL * 8; i += 512) {
        int key = i >> 3, c4 = (i & 7) * 4;
        ushort4 vv = *(const ushort4*)(vg + key * HEADD + c4);
        f16* d = Vts + c4 * VTS + key;
        d[0] = *(const f16*)&vv.x; d[VTS] = *(const f16*)&vv.y;
        d[2 * VTS] = *(const f16*)&vv.z; d[3 * VTS] = *(const f16*)&vv.w;
    }
    for (int i = tid; i < 32 * (LP - LL); i += 512) {
        int ch = i / (LP - LL), key = LL + i % (LP - LL);
        Vts[ch * VTS + key] = (f16)0.f;
    }
    {
        const unsigned int* mg = mtb + (size_t)n * LP * MW;
        for (int i = tid; i < LP * MW; i += 512) mtbL[i] = mg[i];
    }
    __syncthreads();
    f16* Pw = Ps + wave * (16 * PSB);
    const float* bth = biasT + (size_t)h * LP * LP;   // biasT2 layout [88][352][4]
    const v8h ones = {(f16)1.f, (f16)1.f, (f16)1.f, (f16)1.f,
                      (f16)1.f, (f16)1.f, (f16)1.f, (f16)1.f};
    for (int qt = wave; qt < QT; qt += 8) {
        v8h af = *(const v8h*)(qg + (qt * 16 + l15) * HEADD + quad * 8);
        const int r0 = qt * 16 + quad * 4;
        const int rword = r0 >> 5, rsh = r0 & 31;
        const float* bq = bth + (size_t)(qt * 4 + quad) * (LP * 4);
        v4f o0 = {}, o1 = {}, o2 = {};
        // prefetch bias C-init for ktp 0
        v4f cinN[2];
        cinN[0] = *(const v4f*)(bq + (size_t)l15 * 4);
        cinN[1] = *(const v4f*)(bq + (size_t)(16 + l15) * 4);
#pragma unroll
        for (int ktp = 0; ktp < 11; ++ktp) {
            v4f cin[2] = {cinN[0], cinN[1]};
            if (ktp < 10) {   // depth-1 prefetch: overlaps this tile's exp/PV
                cinN[0] = *(const v4f*)(bq + (size_t)((ktp * 2 + 2) * 16 + l15) * 4);
                cinN[1] = *(const v4f*)(bq + (size_t)((ktp * 2 + 3) * 16 + l15) * 4);
            }
            unsigned int mw[2]; v8h bf[2]; v4f s[2];
#pragma unroll
            for (int half = 0; half < 2; ++half) {
                const int col = (ktp * 2 + half) * 16 + l15;
                mw[half] = mtbL[col * MW + rword];
                bf[half] = *(const v8h*)(Ks + col * KS + quad * 8);
            }
#pragma unroll
            for (int half = 0; half < 2; ++half) {
                v4f c = cin[half];
#pragma unroll
                for (int e = 0; e < 4; ++e)
                    if ((mw[half] >> (rsh + e)) & 1u) c[e] = NEGBIG_;
                s[half] = __builtin_amdgcn_mfma_f32_16x16x32_f16(af, bf[half], c, 0, 0, 0);
            }
#pragma unroll
            for (int half = 0; half < 2; ++half)
#pragma unroll
                for (int e = 0; e < 4; ++e) {
                    float p = __builtin_amdgcn_exp2f(s[half][e]);
                    Pw[(quad * 4 + e) * PSB + half * 16 + l15] = (f16)p;
                }
            v8h a  = *(const v8h*)(Pw + l15 * PSB + quad * 8);
            v8h b0 = *(const v8h*)(Vts + l15 * VTS + ktp * 32 + quad * 8);
            v8h b1 = *(const v8h*)(Vts + (16 + l15) * VTS + ktp * 32 + quad * 8);
            o0 = __builtin_amdgcn_mfma_f32_16x16x32_f16(a, b0, o0, 0, 0, 0);
            o1 = __builtin_amdgcn_mfma_f32_16x16x32_f16(a, b1, o1, 0, 0, 0);
            o2 = __builtin_amdgcn_mfma_f32_16x16x32_f16(a, ones, o2, 0, 0, 0);  // row sums
        }
#pragma unroll
        for (int e = 0; e < 4; ++e) {
            int r = r0 + e;
            if (r < LL) {
                float inv = 1.f / o2[e];     // rsum, uniform across l15 lanes
                f16* orow = ao + ((size_t)(n * LL + r)) * DIMD + h * HEADD;
                orow[l15] = (f16)(o0[e] * inv);
                orow[16 + l15] = (f16)(o1[e] * inv);
            }
        }
    }
}

// ---------------- proj GEMM (128x128, async staging, XCD swizzle) ----------------
__global__ __launch_bounds__(256) void proj_gemm(
    const f16* __restrict__ ao, const f16* __restrict__ pwt,
    const float* __restrict__ pb, float* __restrict__ out) {
    __shared__ f16 As[128 * 32];
    __shared__ f16 Bs[128 * 32];
    const int lin = blockIdx.x;
    const int m0 = ((lin / 24) * 8 + (lin & 7)) * 128;
    const int n0 = ((lin >> 3) % 3) * 128;
    const int tid = threadIdx.x;
    const int wave = tid >> 6, lane = tid & 63;
    const int quad = lane >> 4, l15 = lane & 15;
    const int wm = (wave >> 1) * 64, wn = (wave & 1) * 64;
    const int srow = (lane >> 2);
    const int scol = (lane & 3) * 8;
    const f16* ga0 = ao + (size_t)(m0 + wave * 32 + srow) * DIMD + scol;
    const f16* ga1 = ao + (size_t)(m0 + wave * 32 + 16 + srow) * DIMD + scol;
    const f16* gb0 = pwt + (size_t)(n0 + wave * 32 + srow) * DIMD + scol;
    const f16* gb1 = pwt + (size_t)(n0 + wave * 32 + 16 + srow) * DIMD + scol;
    f16* la0 = As + (wave * 2) * 512;
    f16* la1 = As + (wave * 2 + 1) * 512;
    f16* lb0 = Bs + (wave * 2) * 512;
    f16* lb1 = Bs + (wave * 2 + 1) * 512;
    v4f acc[4][4] = {};
    for (int k0 = 0; k0 < DIMD; k0 += 32) {
        async_cp16(ga0 + k0, la0);
        async_cp16(ga1 + k0, la1);
        async_cp16(gb0 + k0, lb0);
        async_cp16(gb1 + k0, lb1);
        __syncthreads();
        v8h a[4], b[4];
#pragma unroll
        for (int i = 0; i < 4; ++i) a[i] = *(const v8h*)(As + (wm + i * 16 + l15) * 32 + quad * 8);
#pragma unroll
        for (int j = 0; j < 4; ++j) b[j] = *(const v8h*)(Bs + (wn + j * 16 + l15) * 32 + quad * 8);
#pragma unroll
        for (int i = 0; i < 4; ++i)
#pragma unroll
            for (int j = 0; j < 4; ++j)
                acc[i][j] = __builtin_amdgcn_mfma_f32_16x16x32_f16(a[i], b[j], acc[i][j], 0, 0, 0);
        __syncthreads();
    }
#pragma unroll
    for (int i = 0; i < 4; ++i)
#pragma unroll
        for (int e = 0; e < 4; ++e) {
            int gm = m0 + wm + i * 16 + quad * 4 + e;
            if (gm < NTOK) {
#pragma unroll
                for (int j = 0; j < 4; ++j) {
                    int gn = n0 + wn + j * 16 + l15;
                    out[(size_t)gm * DIMD + gn] = acc[i][j][e] + pb[gn];
                }
            }
        }
}

extern "C" void kernel_launch(void* const* d_in, const int* in_sizes, int n_in,
                              void* d_out, int out_size, void* d_ws, size_t ws_size,
                              hipStream_t stream) {
    const float* x      = (const float*)d_in[0];
    const float* qkv_w  = (const float*)d_in[1];
    const float* table  = (const float*)d_in[2];
    const float* proj_w = (const float*)d_in[3];
    const float* proj_b = (const float*)d_in[4];
    const int* mask     = (const int*)d_in[5];
    const int* rel      = (const int*)d_in[6];
    float* out = (float*)d_out;
    char* ws = (char*)d_ws;

    f16* q    = (f16*)(ws + OFF_Q);
    f16* k    = (f16*)(ws + OFF_K);
    f16* v    = (f16*)(ws + OFF_V);
    f16* xh   = (f16*)(ws + OFF_AO);   // xh and ao share the [MP][384] buffer
    f16* ao   = (f16*)(ws + OFF_AO);
    float* bt = (float*)(ws + OFF_BT);
    f16* wt   = (f16*)(ws + OFF_WT);
    f16* pwt  = (f16*)(ws + OFF_PWT);
    unsigned int* mtb = (unsigned int*)(ws + OFF_MTB);

    hipFuncSetAttribute((const void*)attn_kernel,
                        hipFuncAttributeMaxDynamicSharedMemorySize, SMEM_ATTN);

    prep_all<<<(SPREP + 255) / 256, 256, 0, stream>>>(
        x, xh, qkv_w, wt, proj_w, pwt, table, rel, bt, mask, mtb);
    qkv_gemm<<<dim3(MPT * 9), 256, 0, stream>>>(xh, wt, q, k, v);
    attn_kernel<<<dim3(NWW, NHH), 512, SMEM_ATTN, stream>>>(q, k, v, bt, mtb, ao);
    proj_gemm<<<dim3(MPT * 3), 256, 0, stream>>>(ao, pwt, proj_b, out);
}